// Round 8
// baseline (473.715 us; speedup 1.0000x reference)
//
#include <hip/hip_runtime.h>
#include <hip/hip_bf16.h>

#define NN 8192
#define FIN 256
#define FO 128
#define ROWS 32                 // rows per block
#define NCH 32                  // 256-col chunks (NN/256)
#define L2E 1.4426950408889634f
#define C2  0.28853900817779268f   // 0.2 * log2(e)

typedef __bf16 bf16x8 __attribute__((ext_vector_type(8)));
typedef __bf16 bf16x2 __attribute__((ext_vector_type(2)));
typedef float  f32x4  __attribute__((ext_vector_type(4)));
typedef unsigned long long u64;
typedef u64 u64x2 __attribute__((ext_vector_type(2)));

__device__ __forceinline__ f32x4 ntload(const float* p) {
  return __builtin_nontemporal_load((const f32x4*)p);
}

// ---------------------------------------------------------------------------
// Kernel 1: h = x@W (fp32 accum), write Bpack (bf16 MFMA-B-fragment layout),
//           f_src = h@a_src, f_dst = h@a_dst (fp32).  (unchanged, proven)
// Bpack element (kg, nt, lane=q*16+m, t) = h[j = kg*32+q*8+t][n = nt*16+m]
// ---------------------------------------------------------------------------
__global__ __launch_bounds__(256) void k_proj(
    const float* __restrict__ x, const float* __restrict__ W,
    const float* __restrict__ a_src, const float* __restrict__ a_dst,
    __bf16* __restrict__ Bp, float* __restrict__ f_src, float* __restrict__ f_dst)
{
  __shared__ float xs[16 * FIN];     // 16 KB x-tile
  __shared__ float fs[16], fd[16];
  const int tid = threadIdx.x;
  const int i0 = blockIdx.x * 16;

  const float4* xg = (const float4*)(x + (size_t)i0 * FIN);
  float4* xs4 = (float4*)xs;
  #pragma unroll
  for (int t = 0; t < 4; t++) xs4[tid + 256 * t] = xg[tid + 256 * t];
  if (tid < 16) { fs[tid] = 0.f; fd[tid] = 0.f; }
  __syncthreads();

  const int cq = tid & 31;    // column quad: cols c0..c0+3
  const int rg = tid >> 5;    // row group: rows r0, r0+1
  const int c0 = cq * 4;
  const int r0 = rg * 2;
  float acc0[4] = {0.f,0.f,0.f,0.f};
  float acc1[4] = {0.f,0.f,0.f,0.f};
  const float* xr0 = xs + r0 * FIN;
  const float* xr1 = xs + (r0 + 1) * FIN;

  for (int k = 0; k < FIN; k += 4) {
    float4 xa = *(const float4*)(xr0 + k);
    float4 xb = *(const float4*)(xr1 + k);
    #pragma unroll
    for (int kk = 0; kk < 4; kk++) {
      float4 wv = *(const float4*)(W + (size_t)(k + kk) * FO + c0);
      float xav = ((const float*)&xa)[kk];
      float xbv = ((const float*)&xb)[kk];
      acc0[0] += xav * wv.x; acc0[1] += xav * wv.y;
      acc0[2] += xav * wv.z; acc0[3] += xav * wv.w;
      acc1[0] += xbv * wv.x; acc1[1] += xbv * wv.y;
      acc1[2] += xbv * wv.z; acc1[3] += xbv * wv.w;
    }
  }

  float4 as = *(const float4*)(a_src + c0);
  float4 ad = *(const float4*)(a_dst + c0);
  float ps0 = acc0[0]*as.x + acc0[1]*as.y + acc0[2]*as.z + acc0[3]*as.w;
  float ps1 = acc1[0]*as.x + acc1[1]*as.y + acc1[2]*as.z + acc1[3]*as.w;
  float pd0 = acc0[0]*ad.x + acc0[1]*ad.y + acc0[2]*ad.z + acc0[3]*ad.w;
  float pd1 = acc1[0]*ad.x + acc1[1]*ad.y + acc1[2]*ad.z + acc1[3]*ad.w;
  atomicAdd(&fs[r0],     ps0);
  atomicAdd(&fs[r0 + 1], ps1);
  atomicAdd(&fd[r0],     pd0);
  atomicAdd(&fd[r0 + 1], pd1);

  const int j0 = i0 + r0;
  const int kg = j0 >> 5;
  const int q  = (j0 >> 3) & 3;
  const int t0 = j0 & 7;
  #pragma unroll
  for (int c = 0; c < 4; c++) {
    const int n = c0 + c;
    bf16x2 v;
    v[0] = (__bf16)acc0[c];
    v[1] = (__bf16)acc1[c];
    size_t idx = ((size_t)(kg * 8 + (n >> 4)) * 64 + q * 16 + (n & 15)) * 8 + t0;
    *(bf16x2*)(Bp + idx) = v;
  }
  __syncthreads();
  if (tid < 16) { f_src[i0 + tid] = fs[tid]; f_dst[i0 + tid] = fd[tid]; }
}

// ---------------------------------------------------------------------------
// Kernel 2: FULL-ROW streaming P@H — sequential pack streams + direct output.
// Round-7 synthesis: k_pack's per-wave SEQUENTIAL row sweep hits 5.2 TB/s;
// every multi-row strided wave pattern hits 1.0-1.5 TB/s. So: block = 32 rows
// x ALL 8192 cols, 8 waves (2 mt x 4 nt-quarters, acc = 2 f32x4 = 8 regs).
// Per 256-col chunk: each wave advances 4 sequential row-streams by 1 KB
// (nontemporal: don't evict Bp from L2/L3), ballots into a double-buffered
// LDS mask, ONE barrier, consume (r7's proven bit-extract + MFMA core, G1/G2
// from a 64 KB LDS table built once). Next chunk's loads issue before
// consume -> HBM latency hides under ~0.9 us compute vs 1.3 us BW budget.
// Output complete per block: shuffle-reduce psum, divide, write out directly.
// Deletes k_div + 128 MB of part traffic. Grid 256 = 1 block/CU.
// ---------------------------------------------------------------------------
__global__ __launch_bounds__(512, 2) void k_attn(
    const float* __restrict__ adj, const __bf16* __restrict__ Bp,
    const float* __restrict__ f_src, const float* __restrict__ f_dst,
    float* __restrict__ out)
{
  __shared__ __align__(16) float G1[NN];            // 32 KB
  __shared__ __align__(16) float G2[NN];            // 32 KB
  __shared__ __align__(16) u64 msk[2][ROWS][5];     // 2.5 KB (stride 5: 2-way max)
  __shared__ float lsum[ROWS];

  const int tid = threadIdx.x;
  const int w = tid >> 6;
  const int lane = tid & 63;
  const int m = lane & 15;
  const int q = lane >> 4;
  const int i0 = blockIdx.x * ROWS;
  const int mt = w >> 2;              // m-tile: rows mt*16 .. mt*16+15
  const int nq = w & 3;               // nt-quarter: output cols nq*32 .. +31

  // Issue chunk-0 adj loads FIRST (latency hides under G-table build).
  // Wave w owns rows w*4..w*4+3; each row advances sequentially chunk-to-chunk.
  const float* abase = adj + (size_t)(i0 + w * 4) * NN + lane * 4;
  f32x4 st0 = ntload(abase);
  f32x4 st1 = ntload(abase + NN);
  f32x4 st2 = ntload(abase + 2 * NN);
  f32x4 st3 = ntload(abase + 3 * NN);

  // G tables for all 8192 cols (once).
  #pragma unroll
  for (int t = 0; t < NN / 512; ++t) {
    int j = t * 512 + tid;
    float d = f_dst[j];
    G1[j] = __builtin_amdgcn_exp2f(d * L2E);
    G2[j] = __builtin_amdgcn_exp2f(d * C2);
  }
  float s = f_src[i0 + mt * 16 + m];
  const float F1 = __builtin_amdgcn_exp2f(s * L2E);
  const float F2 = __builtin_amdgcn_exp2f(s * C2);

  f32x4 acc[2];
  acc[0] = (f32x4){0.f, 0.f, 0.f, 0.f};
  acc[1] = (f32x4){0.f, 0.f, 0.f, 0.f};
  float psum = 0.f;

  const int r0l = mt * 16 + m;

  for (int c = 0; c < NCH; ++c) {
    const int cur = c & 1;

    // ---- ballot-pack this chunk (data dep on st* = the vmcnt wait)
    {
      u64 b0, b1, b2, b3;
      b0 = __ballot(st0[0] > 0.f); b1 = __ballot(st0[1] > 0.f);
      b2 = __ballot(st0[2] > 0.f); b3 = __ballot(st0[3] > 0.f);
      if (lane < 4) msk[cur][w*4+0][lane] = lane==0?b0:lane==1?b1:lane==2?b2:b3;
      b0 = __ballot(st1[0] > 0.f); b1 = __ballot(st1[1] > 0.f);
      b2 = __ballot(st1[2] > 0.f); b3 = __ballot(st1[3] > 0.f);
      if (lane < 4) msk[cur][w*4+1][lane] = lane==0?b0:lane==1?b1:lane==2?b2:b3;
      b0 = __ballot(st2[0] > 0.f); b1 = __ballot(st2[1] > 0.f);
      b2 = __ballot(st2[2] > 0.f); b3 = __ballot(st2[3] > 0.f);
      if (lane < 4) msk[cur][w*4+2][lane] = lane==0?b0:lane==1?b1:lane==2?b2:b3;
      b0 = __ballot(st3[0] > 0.f); b1 = __ballot(st3[1] > 0.f);
      b2 = __ballot(st3[2] > 0.f); b3 = __ballot(st3[3] > 0.f);
      if (lane < 4) msk[cur][w*4+3][lane] = lane==0?b0:lane==1?b1:lane==2?b2:b3;
    }

    // ---- issue next chunk (in flight across the whole consume phase)
    if (c + 1 < NCH) {
      const float* nb = abase + (c + 1) * 256;
      st0 = ntload(nb);
      st1 = ntload(nb + NN);
      st2 = ntload(nb + 2 * NN);
      st3 = ntload(nb + 3 * NN);
    }
    __syncthreads();   // masks(c) visible; single barrier per chunk

    // ---- consume chunk c (r7's proven core, sg folded into c)
    u64x2 Ma01 = *(const u64x2*)&msk[cur][r0l][0];
    u64x2 Ma23 = *(const u64x2*)&msk[cur][r0l][2];
    const u64 M0 = Ma01[0], M1 = Ma01[1], M2 = Ma23[0], M3 = Ma23[1];

    #pragma unroll
    for (int ss = 0; ss < 4; ++ss) {
      #pragma unroll
      for (int kg = 0; kg < 2; ++kg) {
        const int jj = c * 256 + ss * 64 + kg * 32 + q * 8;
        float4 u0 = *(const float4*)(G1 + jj);
        float4 u1 = *(const float4*)(G1 + jj + 4);
        float4 v0 = *(const float4*)(G2 + jj);
        float4 v1 = *(const float4*)(G2 + jj + 4);
        const unsigned b = ss * 16 + kg * 8 + q * 2;   // bit pos (<=62)
        const unsigned e0 = (unsigned)(M0 >> b);
        const unsigned e1 = (unsigned)(M1 >> b);
        const unsigned e2 = (unsigned)(M2 >> b);
        const unsigned e3 = (unsigned)(M3 >> b);
        float p0 = (e0 & 1u) ? fmaxf(F1 * u0.x, F2 * v0.x) : 0.f;
        float p1 = (e1 & 1u) ? fmaxf(F1 * u0.y, F2 * v0.y) : 0.f;
        float p2 = (e2 & 1u) ? fmaxf(F1 * u0.z, F2 * v0.z) : 0.f;
        float p3 = (e3 & 1u) ? fmaxf(F1 * u0.w, F2 * v0.w) : 0.f;
        float p4 = (e0 & 2u) ? fmaxf(F1 * u1.x, F2 * v1.x) : 0.f;
        float p5 = (e1 & 2u) ? fmaxf(F1 * u1.y, F2 * v1.y) : 0.f;
        float p6 = (e2 & 2u) ? fmaxf(F1 * u1.z, F2 * v1.z) : 0.f;
        float p7 = (e3 & 2u) ? fmaxf(F1 * u1.w, F2 * v1.w) : 0.f;
        if (nq == 0)
          psum += ((p0 + p1) + (p2 + p3)) + ((p4 + p5) + (p6 + p7));
        bf16x8 a;
        a[0] = (__bf16)p0; a[1] = (__bf16)p1; a[2] = (__bf16)p2;
        a[3] = (__bf16)p3; a[4] = (__bf16)p4; a[5] = (__bf16)p5;
        a[6] = (__bf16)p6; a[7] = (__bf16)p7;

        const __bf16* bsrc = Bp + (size_t)(c * 8 + ss * 2 + kg) * 4096
                             + (size_t)(nq * 2) * 512 + lane * 8;
        bf16x8 bf0 = *(const bf16x8*)bsrc;
        bf16x8 bf1 = *(const bf16x8*)(bsrc + 512);
        acc[0] = __builtin_amdgcn_mfma_f32_16x16x32_bf16(a, bf0, acc[0], 0, 0, 0);
        acc[1] = __builtin_amdgcn_mfma_f32_16x16x32_bf16(a, bf1, acc[1], 0, 0, 0);
      }
    }
  }

  // ---- epilogue: complete denominators, then direct divided output
  if (nq == 0) {
    float p = psum;
    p += __shfl_xor(p, 16);
    p += __shfl_xor(p, 32);
    if (lane < 16) lsum[mt * 16 + lane] = p;
  }
  __syncthreads();

  // C/D layout: row = q*4 + r (within m-tile), col = (nq*2+nt)*16 + m
  const int rr0 = mt * 16 + q * 4;
  #pragma unroll
  for (int r = 0; r < 4; ++r) {
    const float inv = 1.0f / lsum[rr0 + r];
    float* orow = out + (size_t)(i0 + rr0 + r) * FO + (nq * 2) * 16 + m;
    orow[0]  = acc[0][r] * inv;
    orow[16] = acc[1][r] * inv;
  }
}

extern "C" void kernel_launch(void* const* d_in, const int* in_sizes, int n_in,
                              void* d_out, int out_size, void* d_ws, size_t ws_size,
                              hipStream_t stream) {
  const float* x     = (const float*)d_in[0];
  const float* adj   = (const float*)d_in[1];
  const float* W     = (const float*)d_in[2];
  const float* a_src = (const float*)d_in[3];
  const float* a_dst = (const float*)d_in[4];
  float* out = (float*)d_out;

  char* ws = (char*)d_ws;
  __bf16* Bp   = (__bf16*)ws;                      // 0 .. 2 MB
  float* f_src = (float*)(ws + 2097152);           // 32 KB
  float* f_dst = (float*)(ws + 2097152 + 32768);   // 32 KB

  hipLaunchKernelGGL(k_proj, dim3(512), dim3(256), 0, stream,
                     x, W, a_src, a_dst, Bp, f_src, f_dst);
  hipLaunchKernelGGL(k_attn, dim3(256), dim3(512), 0, stream,
                     adj, Bp, f_src, f_dst, out);
}

// Round 9
// 448.846 us; speedup vs baseline: 1.0554x; 1.0554x over previous
//
#include <hip/hip_runtime.h>
#include <hip/hip_bf16.h>

#define NN 8192
#define FIN 256
#define FO 128
#define ROWS 32                 // rows per block
#define NCH 32                  // 256-col chunks (NN/256)
#define L2E 1.4426950408889634f
#define C2  0.28853900817779268f   // 0.2 * log2(e)

typedef __bf16 bf16x8 __attribute__((ext_vector_type(8)));
typedef __bf16 bf16x2 __attribute__((ext_vector_type(2)));
typedef float  f32x4  __attribute__((ext_vector_type(4)));
typedef unsigned long long u64;
typedef u64 u64x2 __attribute__((ext_vector_type(2)));

__device__ __forceinline__ f32x4 ntload(const float* p) {
  return __builtin_nontemporal_load((const f32x4*)p);
}

// ---------------------------------------------------------------------------
// Kernel 1: h = x@W (fp32 accum), write Bpack (bf16 MFMA-B-fragment layout),
//           f_src = h@a_src, f_dst = h@a_dst (fp32).  (unchanged, proven)
// ---------------------------------------------------------------------------
__global__ __launch_bounds__(256) void k_proj(
    const float* __restrict__ x, const float* __restrict__ W,
    const float* __restrict__ a_src, const float* __restrict__ a_dst,
    __bf16* __restrict__ Bp, float* __restrict__ f_src, float* __restrict__ f_dst)
{
  __shared__ float xs[16 * FIN];     // 16 KB x-tile
  __shared__ float fs[16], fd[16];
  const int tid = threadIdx.x;
  const int i0 = blockIdx.x * 16;

  const float4* xg = (const float4*)(x + (size_t)i0 * FIN);
  float4* xs4 = (float4*)xs;
  #pragma unroll
  for (int t = 0; t < 4; t++) xs4[tid + 256 * t] = xg[tid + 256 * t];
  if (tid < 16) { fs[tid] = 0.f; fd[tid] = 0.f; }
  __syncthreads();

  const int cq = tid & 31;    // column quad: cols c0..c0+3
  const int rg = tid >> 5;    // row group: rows r0, r0+1
  const int c0 = cq * 4;
  const int r0 = rg * 2;
  float acc0[4] = {0.f,0.f,0.f,0.f};
  float acc1[4] = {0.f,0.f,0.f,0.f};
  const float* xr0 = xs + r0 * FIN;
  const float* xr1 = xs + (r0 + 1) * FIN;

  for (int k = 0; k < FIN; k += 4) {
    float4 xa = *(const float4*)(xr0 + k);
    float4 xb = *(const float4*)(xr1 + k);
    #pragma unroll
    for (int kk = 0; kk < 4; kk++) {
      float4 wv = *(const float4*)(W + (size_t)(k + kk) * FO + c0);
      float xav = ((const float*)&xa)[kk];
      float xbv = ((const float*)&xb)[kk];
      acc0[0] += xav * wv.x; acc0[1] += xav * wv.y;
      acc0[2] += xav * wv.z; acc0[3] += xav * wv.w;
      acc1[0] += xbv * wv.x; acc1[1] += xbv * wv.y;
      acc1[2] += xbv * wv.z; acc1[3] += xbv * wv.w;
    }
  }

  float4 as = *(const float4*)(a_src + c0);
  float4 ad = *(const float4*)(a_dst + c0);
  float ps0 = acc0[0]*as.x + acc0[1]*as.y + acc0[2]*as.z + acc0[3]*as.w;
  float ps1 = acc1[0]*as.x + acc1[1]*as.y + acc1[2]*as.z + acc1[3]*as.w;
  float pd0 = acc0[0]*ad.x + acc0[1]*ad.y + acc0[2]*ad.z + acc0[3]*ad.w;
  float pd1 = acc1[0]*ad.x + acc1[1]*ad.y + acc1[2]*ad.z + acc1[3]*ad.w;
  atomicAdd(&fs[r0],     ps0);
  atomicAdd(&fs[r0 + 1], ps1);
  atomicAdd(&fd[r0],     pd0);
  atomicAdd(&fd[r0 + 1], pd1);

  const int j0 = i0 + r0;
  const int kg = j0 >> 5;
  const int q  = (j0 >> 3) & 3;
  const int t0 = j0 & 7;
  #pragma unroll
  for (int c = 0; c < 4; c++) {
    const int n = c0 + c;
    bf16x2 v;
    v[0] = (__bf16)acc0[c];
    v[1] = (__bf16)acc1[c];
    size_t idx = ((size_t)(kg * 8 + (n >> 4)) * 64 + q * 16 + (n & 15)) * 8 + t0;
    *(bf16x2*)(Bp + idx) = v;
  }
  __syncthreads();
  if (tid < 16) { f_src[i0 + tid] = fs[tid]; f_dst[i0 + tid] = fd[tid]; }
}

// ---------------------------------------------------------------------------
// Kernel 2: producer/consumer wave-specialized P@H.
// Round-8 root cause: (a) per-chunk __syncthreads drains vmcnt(0) -> every
// chunk pays full HBM latency; (b) FIFO vmcnt means consume's Bp-load->MFMA
// waits ALSO drain older in-flight adj loads. Both fixed by putting adj
// (HBM) and Bp (L2) dependencies in DIFFERENT waves' counters:
//   waves 8-9 = producers: stream 16 adj rows each as contiguous 1 KB
//     wave-loads (16 in flight, progressive counted vmcnt), ballot-pack into
//     double-buffered LDS msk, sync with lgkmcnt(0) + RAW s_barrier (no
//     vmcnt drain -> prefetch lives across the barrier).
//   waves 0-7 = consumers: round-8's consume core verbatim (2 mt x 4 nq);
//     their __syncthreads drains only fast L2 Bp loads.
// Ring: 2 slots, producer leads consumers by 1 phase. Barriers: 34 per wave
// on both paths. Output written directly (no partials, no k_div).
// ---------------------------------------------------------------------------
__global__ __launch_bounds__(640) void k_attn(
    const float* __restrict__ adj, const __bf16* __restrict__ Bp,
    const float* __restrict__ f_src, const float* __restrict__ f_dst,
    float* __restrict__ out)
{
  __shared__ __align__(16) float G1[NN];            // 32 KB
  __shared__ __align__(16) float G2[NN];            // 32 KB
  __shared__ __align__(16) u64 msk[2][ROWS][5];     // 2.5 KB
  __shared__ float lsum[ROWS];

  const int tid = threadIdx.x;
  const int w = tid >> 6;
  const int lane = tid & 63;
  const int i0 = blockIdx.x * ROWS;

  if (w >= 8) {
    // ================= PRODUCER (waves 8,9) =================
    const int pw = w - 8;                 // rows pw*16 .. pw*16+15
    const int prow0 = pw * 16;
    const float* abase = adj + (size_t)(i0 + prow0) * NN + lane * 4;

    f32x4 s0,s1,s2,s3,s4,s5,s6,s7,s8,s9,s10,s11,s12,s13,s14,s15;

#define PLOAD(c) {                                                            \
    const float* _b = abase + (size_t)(c) * 256;                              \
    s0=ntload(_b);        s1=ntload(_b+NN);       s2=ntload(_b+2*NN);         \
    s3=ntload(_b+3*NN);   s4=ntload(_b+4*NN);     s5=ntload(_b+5*NN);         \
    s6=ntload(_b+6*NN);   s7=ntload(_b+7*NN);     s8=ntload(_b+8*NN);         \
    s9=ntload(_b+9*NN);   s10=ntload(_b+10*NN);   s11=ntload(_b+11*NN);       \
    s12=ntload(_b+12*NN); s13=ntload(_b+13*NN);   s14=ntload(_b+14*NN);       \
    s15=ntload(_b+15*NN); }

#define PROW(sv, slot, r) {                                                   \
    u64 b0=__ballot(sv[0]>0.f), b1=__ballot(sv[1]>0.f);                       \
    u64 b2=__ballot(sv[2]>0.f), b3=__ballot(sv[3]>0.f);                       \
    if (lane < 4)                                                             \
      msk[slot][prow0 + (r)][lane] = lane==0?b0:lane==1?b1:lane==2?b2:b3; }

#define PPACK(slot) {                                                         \
    PROW(s0,slot,0)  PROW(s1,slot,1)  PROW(s2,slot,2)  PROW(s3,slot,3)        \
    PROW(s4,slot,4)  PROW(s5,slot,5)  PROW(s6,slot,6)  PROW(s7,slot,7)        \
    PROW(s8,slot,8)  PROW(s9,slot,9)  PROW(s10,slot,10) PROW(s11,slot,11)     \
    PROW(s12,slot,12) PROW(s13,slot,13) PROW(s14,slot,14) PROW(s15,slot,15) }

    PLOAD(0)
    PPACK(0)                      // chunk 0 -> slot 0
    PLOAD(1)
    asm volatile("s_waitcnt lgkmcnt(0)" ::: "memory");
    __builtin_amdgcn_s_barrier();                    // barrier #0
    __builtin_amdgcn_sched_barrier(0);

    for (int k = 0; k < NCH; ++k) {
      if (k + 1 < NCH) {
        PPACK((k + 1) & 1)        // pack chunk k+1 (regs from prev PLOAD)
        if (k + 2 < NCH) PLOAD(k + 2)
      }
      asm volatile("s_waitcnt lgkmcnt(0)" ::: "memory");
      __builtin_amdgcn_s_barrier();                  // phase barrier (no vmcnt drain)
      __builtin_amdgcn_sched_barrier(0);
    }
    __syncthreads();              // epilogue barrier (pairs with consumers)
#undef PLOAD
#undef PROW
#undef PPACK
  } else {
    // ================= CONSUMER (waves 0..7) =================
    const int m = lane & 15;
    const int q = lane >> 4;
    const int mt = w >> 2;              // m-tile: rows mt*16 .. mt*16+15
    const int nq = w & 3;               // nt-quarter: output cols nq*32 .. +31

    // G tables for all 8192 cols (consumers only: 512 threads)
    const int ctid = tid;               // 0..511
    #pragma unroll
    for (int t = 0; t < NN / 512; ++t) {
      int j = t * 512 + ctid;
      float d = f_dst[j];
      G1[j] = __builtin_amdgcn_exp2f(d * L2E);
      G2[j] = __builtin_amdgcn_exp2f(d * C2);
    }
    float s = f_src[i0 + mt * 16 + m];
    const float F1 = __builtin_amdgcn_exp2f(s * L2E);
    const float F2 = __builtin_amdgcn_exp2f(s * C2);

    f32x4 acc0 = (f32x4){0.f, 0.f, 0.f, 0.f};
    f32x4 acc1 = (f32x4){0.f, 0.f, 0.f, 0.f};
    float psum = 0.f;
    const int r0l = mt * 16 + m;

    __syncthreads();                                 // barrier #0

    for (int c = 0; c < NCH; ++c) {
      const int cur = c & 1;
      u64x2 Ma01 = *(const u64x2*)&msk[cur][r0l][0];
      u64x2 Ma23 = *(const u64x2*)&msk[cur][r0l][2];
      const u64 M0 = Ma01[0], M1 = Ma01[1], M2 = Ma23[0], M3 = Ma23[1];

      #pragma unroll
      for (int ss = 0; ss < 4; ++ss) {
        #pragma unroll
        for (int kg = 0; kg < 2; ++kg) {
          const int jj = c * 256 + ss * 64 + kg * 32 + q * 8;
          float4 u0 = *(const float4*)(G1 + jj);
          float4 u1 = *(const float4*)(G1 + jj + 4);
          float4 v0 = *(const float4*)(G2 + jj);
          float4 v1 = *(const float4*)(G2 + jj + 4);
          const unsigned b = ss * 16 + kg * 8 + q * 2;   // bit pos (<=62)
          const unsigned e0 = (unsigned)(M0 >> b);
          const unsigned e1 = (unsigned)(M1 >> b);
          const unsigned e2 = (unsigned)(M2 >> b);
          const unsigned e3 = (unsigned)(M3 >> b);
          float p0 = (e0 & 1u) ? fmaxf(F1 * u0.x, F2 * v0.x) : 0.f;
          float p1 = (e1 & 1u) ? fmaxf(F1 * u0.y, F2 * v0.y) : 0.f;
          float p2 = (e2 & 1u) ? fmaxf(F1 * u0.z, F2 * v0.z) : 0.f;
          float p3 = (e3 & 1u) ? fmaxf(F1 * u0.w, F2 * v0.w) : 0.f;
          float p4 = (e0 & 2u) ? fmaxf(F1 * u1.x, F2 * v1.x) : 0.f;
          float p5 = (e1 & 2u) ? fmaxf(F1 * u1.y, F2 * v1.y) : 0.f;
          float p6 = (e2 & 2u) ? fmaxf(F1 * u1.z, F2 * v1.z) : 0.f;
          float p7 = (e3 & 2u) ? fmaxf(F1 * u1.w, F2 * v1.w) : 0.f;
          if (nq == 0)
            psum += ((p0 + p1) + (p2 + p3)) + ((p4 + p5) + (p6 + p7));
          bf16x8 a;
          a[0] = (__bf16)p0; a[1] = (__bf16)p1; a[2] = (__bf16)p2;
          a[3] = (__bf16)p3; a[4] = (__bf16)p4; a[5] = (__bf16)p5;
          a[6] = (__bf16)p6; a[7] = (__bf16)p7;

          const __bf16* bsrc = Bp + (size_t)(c * 8 + ss * 2 + kg) * 4096
                               + (size_t)(nq * 2) * 512 + lane * 8;
          bf16x8 bf0 = *(const bf16x8*)bsrc;
          bf16x8 bf1 = *(const bf16x8*)(bsrc + 512);
          acc0 = __builtin_amdgcn_mfma_f32_16x16x32_bf16(a, bf0, acc0, 0, 0, 0);
          acc1 = __builtin_amdgcn_mfma_f32_16x16x32_bf16(a, bf1, acc1, 0, 0, 0);
        }
      }
      __syncthreads();            // phase barrier (drains only fast Bp loads)
    }

    // ---- epilogue: denominators, then direct divided output
    if (nq == 0) {
      float p = psum;
      p += __shfl_xor(p, 16);
      p += __shfl_xor(p, 32);
      if (lane < 16) lsum[mt * 16 + lane] = p;
    }
    __syncthreads();              // epilogue barrier

    const int rr0 = mt * 16 + q * 4;
    #pragma unroll
    for (int r = 0; r < 4; ++r) {
      const float inv = 1.0f / lsum[rr0 + r];
      float* orow = out + (size_t)(i0 + rr0 + r) * FO + (nq * 2) * 16 + m;
      orow[0]  = acc0[r] * inv;
      orow[16] = acc1[r] * inv;
    }
  }
}

extern "C" void kernel_launch(void* const* d_in, const int* in_sizes, int n_in,
                              void* d_out, int out_size, void* d_ws, size_t ws_size,
                              hipStream_t stream) {
  const float* x     = (const float*)d_in[0];
  const float* adj   = (const float*)d_in[1];
  const float* W     = (const float*)d_in[2];
  const float* a_src = (const float*)d_in[3];
  const float* a_dst = (const float*)d_in[4];
  float* out = (float*)d_out;

  char* ws = (char*)d_ws;
  __bf16* Bp   = (__bf16*)ws;                      // 0 .. 2 MB
  float* f_src = (float*)(ws + 2097152);           // 32 KB
  float* f_dst = (float*)(ws + 2097152 + 32768);   // 32 KB

  hipLaunchKernelGGL(k_proj, dim3(512), dim3(256), 0, stream,
                     x, W, a_src, a_dst, Bp, f_src, f_dst);
  hipLaunchKernelGGL(k_attn, dim3(256), dim3(640), 0, stream,
                     adj, Bp, f_src, f_dst, out);
}

// Round 10
// 402.946 us; speedup vs baseline: 1.1756x; 1.1139x over previous
//
#include <hip/hip_runtime.h>
#include <hip/hip_bf16.h>

#define NN 8192
#define FIN 256
#define FO 128
#define ROWS 32                 // rows per block
#define NCH 32                  // 256-col chunks (NN/256)
#define L2E 1.4426950408889634f
#define C2  0.28853900817779268f   // 0.2 * log2(e)

typedef __bf16 bf16x8 __attribute__((ext_vector_type(8)));
typedef __bf16 bf16x2 __attribute__((ext_vector_type(2)));
typedef float  f32x4  __attribute__((ext_vector_type(4)));
typedef unsigned long long u64;
typedef u64 u64x2 __attribute__((ext_vector_type(2)));

__device__ __forceinline__ f32x4 ntload(const float* p) {
  return __builtin_nontemporal_load((const f32x4*)p);
}

// ---------------------------------------------------------------------------
// Kernel 1: h = x@W (fp32 accum), write Bpack (bf16 MFMA-B-fragment layout),
//           f_src = h@a_src, f_dst = h@a_dst (fp32).  (unchanged, proven)
// ---------------------------------------------------------------------------
__global__ __launch_bounds__(256) void k_proj(
    const float* __restrict__ x, const float* __restrict__ W,
    const float* __restrict__ a_src, const float* __restrict__ a_dst,
    __bf16* __restrict__ Bp, float* __restrict__ f_src, float* __restrict__ f_dst)
{
  __shared__ float xs[16 * FIN];     // 16 KB x-tile
  __shared__ float fs[16], fd[16];
  const int tid = threadIdx.x;
  const int i0 = blockIdx.x * 16;

  const float4* xg = (const float4*)(x + (size_t)i0 * FIN);
  float4* xs4 = (float4*)xs;
  #pragma unroll
  for (int t = 0; t < 4; t++) xs4[tid + 256 * t] = xg[tid + 256 * t];
  if (tid < 16) { fs[tid] = 0.f; fd[tid] = 0.f; }
  __syncthreads();

  const int cq = tid & 31;    // column quad: cols c0..c0+3
  const int rg = tid >> 5;    // row group: rows r0, r0+1
  const int c0 = cq * 4;
  const int r0 = rg * 2;
  float acc0[4] = {0.f,0.f,0.f,0.f};
  float acc1[4] = {0.f,0.f,0.f,0.f};
  const float* xr0 = xs + r0 * FIN;
  const float* xr1 = xs + (r0 + 1) * FIN;

  for (int k = 0; k < FIN; k += 4) {
    float4 xa = *(const float4*)(xr0 + k);
    float4 xb = *(const float4*)(xr1 + k);
    #pragma unroll
    for (int kk = 0; kk < 4; kk++) {
      float4 wv = *(const float4*)(W + (size_t)(k + kk) * FO + c0);
      float xav = ((const float*)&xa)[kk];
      float xbv = ((const float*)&xb)[kk];
      acc0[0] += xav * wv.x; acc0[1] += xav * wv.y;
      acc0[2] += xav * wv.z; acc0[3] += xav * wv.w;
      acc1[0] += xbv * wv.x; acc1[1] += xbv * wv.y;
      acc1[2] += xbv * wv.z; acc1[3] += xbv * wv.w;
    }
  }

  float4 as = *(const float4*)(a_src + c0);
  float4 ad = *(const float4*)(a_dst + c0);
  float ps0 = acc0[0]*as.x + acc0[1]*as.y + acc0[2]*as.z + acc0[3]*as.w;
  float ps1 = acc1[0]*as.x + acc1[1]*as.y + acc1[2]*as.z + acc1[3]*as.w;
  float pd0 = acc0[0]*ad.x + acc0[1]*ad.y + acc0[2]*ad.z + acc0[3]*ad.w;
  float pd1 = acc1[0]*ad.x + acc1[1]*ad.y + acc1[2]*ad.z + acc1[3]*ad.w;
  atomicAdd(&fs[r0],     ps0);
  atomicAdd(&fs[r0 + 1], ps1);
  atomicAdd(&fd[r0],     pd0);
  atomicAdd(&fd[r0 + 1], pd1);

  const int j0 = i0 + r0;
  const int kg = j0 >> 5;
  const int q  = (j0 >> 3) & 3;
  const int t0 = j0 & 7;
  #pragma unroll
  for (int c = 0; c < 4; c++) {
    const int n = c0 + c;
    bf16x2 v;
    v[0] = (__bf16)acc0[c];
    v[1] = (__bf16)acc1[c];
    size_t idx = ((size_t)(kg * 8 + (n >> 4)) * 64 + q * 16 + (n & 15)) * 8 + t0;
    *(bf16x2*)(Bp + idx) = v;
  }
  __syncthreads();
  if (tid < 16) { f_src[i0 + tid] = fs[tid]; f_dst[i0 + tid] = fd[tid]; }
}

// ---------------------------------------------------------------------------
// Kernel 2: producer/consumer P@H with DE-DUPLICATED softmax + pipelined Bp.
// Round-9 budget (from r8 counters): VALU-issue ~68us of which 3/4 is the
// 4x-redundant a-frag p-compute (all nq waves of an mt recompute identical
// frags); plus ~30-50us of JIT-issued Bp L2 latency (VGPR=56, nothing
// hoisted). Fix:
//  - two-phase chunks: phase A = 8 consumer waves compute 16 DISTINCT
//    a-frags (task=(mt,ss,kg)), ds_write to double-buffered af[] (32KB);
//    barrier; phase B = wave (mt,nq) ds_reads af + MFMA, with Bp loads
//    issued 4-deep (static regs) so L2 latency amortizes.
//  - producers (waves 8,9) unchanged from r9: raw s_barrier + lgkm only,
//    adj prefetch lives across barriers. 34 barriers on all paths.
// Arithmetic per element identical; psum grouping differs (tolerance ok).
// ---------------------------------------------------------------------------
__global__ __launch_bounds__(640) void k_attn(
    const float* __restrict__ adj, const __bf16* __restrict__ Bp,
    const float* __restrict__ f_src, const float* __restrict__ f_dst,
    float* __restrict__ out)
{
  __shared__ __align__(16) float G1[NN];                 // 32 KB
  __shared__ __align__(16) float G2[NN];                 // 32 KB
  __shared__ __align__(16) u64 msk[2][ROWS][5];          // 2.5 KB
  __shared__ __align__(16) __bf16 af[2][2][8][64][8];    // 32 KB a-frags
  __shared__ float lsum[ROWS];

  const int tid = threadIdx.x;
  const int w = tid >> 6;
  const int lane = tid & 63;
  const int i0 = blockIdx.x * ROWS;

  if (w >= 8) {
    // ================= PRODUCER (waves 8,9) =================
    const int pw = w - 8;                 // rows pw*16 .. pw*16+15
    const int prow0 = pw * 16;
    const float* abase = adj + (size_t)(i0 + prow0) * NN + lane * 4;

    f32x4 s0,s1,s2,s3,s4,s5,s6,s7,s8,s9,s10,s11,s12,s13,s14,s15;

#define PLOAD(c) {                                                            \
    const float* _b = abase + (size_t)(c) * 256;                              \
    s0=ntload(_b);        s1=ntload(_b+NN);       s2=ntload(_b+2*NN);         \
    s3=ntload(_b+3*NN);   s4=ntload(_b+4*NN);     s5=ntload(_b+5*NN);         \
    s6=ntload(_b+6*NN);   s7=ntload(_b+7*NN);     s8=ntload(_b+8*NN);         \
    s9=ntload(_b+9*NN);   s10=ntload(_b+10*NN);   s11=ntload(_b+11*NN);       \
    s12=ntload(_b+12*NN); s13=ntload(_b+13*NN);   s14=ntload(_b+14*NN);       \
    s15=ntload(_b+15*NN); }

#define PROW(sv, slot, r) {                                                   \
    u64 b0=__ballot(sv[0]>0.f), b1=__ballot(sv[1]>0.f);                       \
    u64 b2=__ballot(sv[2]>0.f), b3=__ballot(sv[3]>0.f);                       \
    if (lane < 4)                                                             \
      msk[slot][prow0 + (r)][lane] = lane==0?b0:lane==1?b1:lane==2?b2:b3; }

#define PPACK(slot) {                                                         \
    PROW(s0,slot,0)  PROW(s1,slot,1)  PROW(s2,slot,2)  PROW(s3,slot,3)        \
    PROW(s4,slot,4)  PROW(s5,slot,5)  PROW(s6,slot,6)  PROW(s7,slot,7)        \
    PROW(s8,slot,8)  PROW(s9,slot,9)  PROW(s10,slot,10) PROW(s11,slot,11)     \
    PROW(s12,slot,12) PROW(s13,slot,13) PROW(s14,slot,14) PROW(s15,slot,15) }

    PLOAD(0)
    PPACK(0)                      // chunk 0 -> slot 0
    PLOAD(1)
    asm volatile("s_waitcnt lgkmcnt(0)" ::: "memory");
    __builtin_amdgcn_s_barrier();                    // barrier #0
    __builtin_amdgcn_sched_barrier(0);

    for (int k = 0; k < NCH; ++k) {
      if (k + 1 < NCH) {
        PPACK((k + 1) & 1)        // pack chunk k+1 (regs from prev PLOAD)
        if (k + 2 < NCH) PLOAD(k + 2)
      }
      asm volatile("s_waitcnt lgkmcnt(0)" ::: "memory");
      __builtin_amdgcn_s_barrier();                  // phase barrier (no vmcnt drain)
      __builtin_amdgcn_sched_barrier(0);
    }
    __syncthreads();              // epilogue barrier (pairs with consumers)
#undef PLOAD
#undef PROW
#undef PPACK
  } else {
    // ================= CONSUMER (waves 0..7) =================
    const int m = lane & 15;
    const int q = lane >> 4;
    const int mt = w >> 2;              // m-tile: rows mt*16 .. mt*16+15
    const int ss = w & 3;               // phase-A task: 64-col step within chunk
    const int nq = w & 3;               // phase-B role: output cols nq*32 .. +31

    // G tables for all 8192 cols (consumers only: 512 threads)
    #pragma unroll
    for (int t = 0; t < NN / 512; ++t) {
      int j = t * 512 + tid;
      float d = f_dst[j];
      G1[j] = __builtin_amdgcn_exp2f(d * L2E);
      G2[j] = __builtin_amdgcn_exp2f(d * C2);
    }
    if (tid < ROWS) lsum[tid] = 0.f;
    float s = f_src[i0 + mt * 16 + m];
    const float F1 = __builtin_amdgcn_exp2f(s * L2E);
    const float F2 = __builtin_amdgcn_exp2f(s * C2);

    f32x4 acc0 = (f32x4){0.f, 0.f, 0.f, 0.f};
    f32x4 acc1 = (f32x4){0.f, 0.f, 0.f, 0.f};
    float psum = 0.f;
    const int r0l = mt * 16 + m;

    __syncthreads();                                 // barrier #0

    for (int c = 0; c < NCH; ++c) {
      const int cur = c & 1;

      // ---- phase A: compute my 2 a-frags (task = mt, ss, kg=0..1), ONCE
      {
        u64x2 Ma01 = *(const u64x2*)&msk[cur][r0l][0];
        u64x2 Ma23 = *(const u64x2*)&msk[cur][r0l][2];
        const u64 M0 = Ma01[0], M1 = Ma01[1], M2 = Ma23[0], M3 = Ma23[1];
        #pragma unroll
        for (int kg = 0; kg < 2; ++kg) {
          const int jj = c * 256 + ss * 64 + kg * 32 + q * 8;
          float4 u0 = *(const float4*)(G1 + jj);
          float4 u1 = *(const float4*)(G1 + jj + 4);
          float4 v0 = *(const float4*)(G2 + jj);
          float4 v1 = *(const float4*)(G2 + jj + 4);
          const unsigned b = ss * 16 + kg * 8 + q * 2;   // bit pos (<=62)
          const unsigned e0 = (unsigned)(M0 >> b);
          const unsigned e1 = (unsigned)(M1 >> b);
          const unsigned e2 = (unsigned)(M2 >> b);
          const unsigned e3 = (unsigned)(M3 >> b);
          float p0 = (e0 & 1u) ? fmaxf(F1 * u0.x, F2 * v0.x) : 0.f;
          float p1 = (e1 & 1u) ? fmaxf(F1 * u0.y, F2 * v0.y) : 0.f;
          float p2 = (e2 & 1u) ? fmaxf(F1 * u0.z, F2 * v0.z) : 0.f;
          float p3 = (e3 & 1u) ? fmaxf(F1 * u0.w, F2 * v0.w) : 0.f;
          float p4 = (e0 & 2u) ? fmaxf(F1 * u1.x, F2 * v1.x) : 0.f;
          float p5 = (e1 & 2u) ? fmaxf(F1 * u1.y, F2 * v1.y) : 0.f;
          float p6 = (e2 & 2u) ? fmaxf(F1 * u1.z, F2 * v1.z) : 0.f;
          float p7 = (e3 & 2u) ? fmaxf(F1 * u1.w, F2 * v1.w) : 0.f;
          psum += ((p0 + p1) + (p2 + p3)) + ((p4 + p5) + (p6 + p7));
          bf16x8 a;
          a[0] = (__bf16)p0; a[1] = (__bf16)p1; a[2] = (__bf16)p2;
          a[3] = (__bf16)p3; a[4] = (__bf16)p4; a[5] = (__bf16)p5;
          a[6] = (__bf16)p6; a[7] = (__bf16)p7;
          *(bf16x8*)&af[cur][mt][ss * 2 + kg][lane][0] = a;
        }
      }
      __syncthreads();             // af[cur] + msk[c+1] ready

      // ---- phase B: MFMA my (mt, nq) quarter over all 8 kg of this chunk.
      // Bp loads issued 4-deep per half so L2 latency amortizes.
      {
        const __bf16* bch = Bp + (size_t)c * 8 * 4096 + (size_t)(nq * 2) * 512 + lane * 8;
        const bf16x8* afp = (const bf16x8*)&af[cur][mt][0][lane][0];  // stride 64/frag
        #pragma unroll
        for (int h = 0; h < 2; ++h) {
          bf16x8 b00 = *(const bf16x8*)(bch + (h * 4 + 0) * 4096);
          bf16x8 b10 = *(const bf16x8*)(bch + (h * 4 + 0) * 4096 + 512);
          bf16x8 b01 = *(const bf16x8*)(bch + (h * 4 + 1) * 4096);
          bf16x8 b11 = *(const bf16x8*)(bch + (h * 4 + 1) * 4096 + 512);
          bf16x8 b02 = *(const bf16x8*)(bch + (h * 4 + 2) * 4096);
          bf16x8 b12 = *(const bf16x8*)(bch + (h * 4 + 2) * 4096 + 512);
          bf16x8 b03 = *(const bf16x8*)(bch + (h * 4 + 3) * 4096);
          bf16x8 b13 = *(const bf16x8*)(bch + (h * 4 + 3) * 4096 + 512);
          bf16x8 a0 = afp[(h * 4 + 0) * 64];
          bf16x8 a1 = afp[(h * 4 + 1) * 64];
          bf16x8 a2 = afp[(h * 4 + 2) * 64];
          bf16x8 a3 = afp[(h * 4 + 3) * 64];
          acc0 = __builtin_amdgcn_mfma_f32_16x16x32_bf16(a0, b00, acc0, 0, 0, 0);
          acc1 = __builtin_amdgcn_mfma_f32_16x16x32_bf16(a0, b10, acc1, 0, 0, 0);
          acc0 = __builtin_amdgcn_mfma_f32_16x16x32_bf16(a1, b01, acc0, 0, 0, 0);
          acc1 = __builtin_amdgcn_mfma_f32_16x16x32_bf16(a1, b11, acc1, 0, 0, 0);
          acc0 = __builtin_amdgcn_mfma_f32_16x16x32_bf16(a2, b02, acc0, 0, 0, 0);
          acc1 = __builtin_amdgcn_mfma_f32_16x16x32_bf16(a2, b12, acc1, 0, 0, 0);
          acc0 = __builtin_amdgcn_mfma_f32_16x16x32_bf16(a3, b03, acc0, 0, 0, 0);
          acc1 = __builtin_amdgcn_mfma_f32_16x16x32_bf16(a3, b13, acc1, 0, 0, 0);
        }
      }
    }

    // ---- epilogue: denominators (each row touched by 4 ss-waves), output
    {
      float p = psum;
      p += __shfl_xor(p, 16);
      p += __shfl_xor(p, 32);
      if (lane < 16) atomicAdd(&lsum[mt * 16 + lane], p);
    }
    __syncthreads();              // epilogue barrier (#34)

    const int rr0 = mt * 16 + q * 4;
    #pragma unroll
    for (int r = 0; r < 4; ++r) {
      const float inv = 1.0f / lsum[rr0 + r];
      float* orow = out + (size_t)(i0 + rr0 + r) * FO + (nq * 2) * 16 + m;
      orow[0]  = acc0[r] * inv;
      orow[16] = acc1[r] * inv;
    }
  }
}

extern "C" void kernel_launch(void* const* d_in, const int* in_sizes, int n_in,
                              void* d_out, int out_size, void* d_ws, size_t ws_size,
                              hipStream_t stream) {
  const float* x     = (const float*)d_in[0];
  const float* adj   = (const float*)d_in[1];
  const float* W     = (const float*)d_in[2];
  const float* a_src = (const float*)d_in[3];
  const float* a_dst = (const float*)d_in[4];
  float* out = (float*)d_out;

  char* ws = (char*)d_ws;
  __bf16* Bp   = (__bf16*)ws;                      // 0 .. 2 MB
  float* f_src = (float*)(ws + 2097152);           // 32 KB
  float* f_dst = (float*)(ws + 2097152 + 32768);   // 32 KB

  hipLaunchKernelGGL(k_proj, dim3(512), dim3(256), 0, stream,
                     x, W, a_src, a_dst, Bp, f_src, f_dst);
  hipLaunchKernelGGL(k_attn, dim3(256), dim3(640), 0, stream,
                     adj, Bp, f_src, f_dst, out);
}